// Round 15
// baseline (481.458 us; speedup 1.0000x reference)
//
#include <hip/hip_runtime.h>
#include <hip/hip_bf16.h>
#include <cmath>

#define HH 768
#define WW 768
#define HWSZ (768*768)

typedef __attribute__((ext_vector_type(8))) short bhalf8;   // 8 bf16 in 4 VGPRs
typedef __attribute__((ext_vector_type(4))) float f32x4;
typedef __attribute__((ext_vector_type(16))) float f32x16;

__device__ inline ushort f2bf(float f) {
  __hip_bfloat16 h = __float2bfloat16(f);
  return *reinterpret_cast<ushort*>(&h);
}
__device__ inline float bf2f(ushort u) {
  union { unsigned int i; float f; } v; v.i = ((unsigned int)u) << 16; return v.f;
}

// ---------------- merged weight transform for all 4 heads ----------------
__global__ __launch_bounds__(256) void wxform_all_kernel(
    const float* __restrict__ w1S, const float* __restrict__ b1S,
    const float* __restrict__ sS,  const float* __restrict__ tS,
    const float* __restrict__ w1L, const float* __restrict__ b1L,
    const float* __restrict__ sL,  const float* __restrict__ tL,
    const float* __restrict__ w1F, const float* __restrict__ b1F,
    const float* __restrict__ sF,  const float* __restrict__ tF,
    const float* __restrict__ w1R, const float* __restrict__ b1R,
    const float* __restrict__ sR,  const float* __restrict__ tR,
    ushort* __restrict__ wT0, float* __restrict__ bb0, size_t wt_stride_elems)
{
  int h = blockIdx.y;
  const float *w1, *b1, *s, *t;
  int npos;
  if (h == 0)      { w1 = w1S; b1 = b1S; s = sS; t = tS; npos = 9;  }
  else if (h == 1) { w1 = w1L; b1 = b1L; s = sL; t = tL; npos = 49; }
  else if (h == 2) { w1 = w1F; b1 = b1F; s = sF; t = tF; npos = 49; }
  else             { w1 = w1R; b1 = b1R; s = sR; t = tR; npos = 49; }

  ushort* wT = wT0 + (size_t)h * wt_stride_elems;
  float*  bb = bb0 + h * 32;

  int i = blockIdx.x * 256 + threadIdx.x;
  if (i < npos * 1024) {
    int pos = i >> 10, mc = i & 1023, m = mc >> 5, c = mc & 31;
    wT[i] = f2bf(w1[(m * 32 + c) * npos + pos] * s[m]);
  }
  if (blockIdx.x == 0 && i < 32) bb[i] = b1[i] * s[i] + t[i];
}

// ---------------- backbone: conv3x3 (3->32) + bias + relu, feats[b][y][x][c] bf16 ----------------
__global__ __launch_bounds__(256) void backbone_kernel(
    const float* __restrict__ x, const float* __restrict__ w,
    const float* __restrict__ bias, ushort* __restrict__ feats)
{
  int p = blockIdx.x * 256 + threadIdx.x;          // 0 .. 2*HW-1
  int bb  = p / HWSZ;
  int rem = p - bb * HWSZ;
  int y   = rem / WW;
  int xx  = rem - y * WW;
  const float* xb = x + (size_t)bb * 3 * HWSZ;

  float v[3][3][3];
  #pragma unroll
  for (int c = 0; c < 3; c++)
    #pragma unroll
    for (int dy = 0; dy < 3; dy++)
      #pragma unroll
      for (int dx = 0; dx < 3; dx++) {
        int yy = y + dy - 1, xq = xx + dx - 1;
        v[c][dy][dx] = (yy >= 0 && yy < HH && xq >= 0 && xq < WW)
                         ? xb[(size_t)c * HWSZ + yy * WW + xq] : 0.f;
      }

  union { ushort u[32]; uint4 q[4]; } pk;
  #pragma unroll
  for (int o = 0; o < 32; o++) {
    float acc = bias[o];
    #pragma unroll
    for (int c = 0; c < 3; c++)
      #pragma unroll
      for (int dy = 0; dy < 3; dy++)
        #pragma unroll
        for (int dx = 0; dx < 3; dx++)
          acc = fmaf(w[((o * 3 + c) * 3 + dy) * 3 + dx], v[c][dy][dx], acc);
    pk.u[o] = f2bf(fmaxf(acc, 0.f));
  }
  uint4* dst = (uint4*)(feats + ((size_t)bb * HWSZ + rem) * 32);
  #pragma unroll
  for (int i = 0; i < 4; i++) dst[i] = pk.q[i];
}

// ---------------- heads3 epilogue: BN+relu -> bf16 mids in LDS -> 1x1 conv -> store ----
template <int COUT, bool DO_TANH>
__device__ inline void head_epilogue3(
    const f32x16 acc[2], const float* __restrict__ bbh,
    const float* __restrict__ w2, const float* __restrict__ b2,
    float* __restrict__ out_base, ushort* mid,
    int wv, int qr, int qc, int kg, int by, int bx, int bb)
{
  #pragma unroll
  for (int n = 0; n < 2; n++) {
    int px = (2 * wv + qr) * 32 + n * 16 + qc;
    #pragma unroll
    for (int rg = 0; rg < 4; rg++) {
      int m0 = 8 * rg + 4 * kg;
      ushort u[4];
      #pragma unroll
      for (int j = 0; j < 4; j++)
        u[j] = f2bf(fmaxf(acc[n][rg * 4 + j] + bbh[m0 + j], 0.f));
      uint2 pkv;
      pkv.x = (unsigned int)u[0] | ((unsigned int)u[1] << 16);
      pkv.y = (unsigned int)u[2] | ((unsigned int)u[3] << 16);
      *(uint2*)(mid + px * 36 + m0) = pkv;
    }
  }
  __syncthreads();

  int t = threadIdx.x;                       // one pixel per thread (512 px)
  float mv[32];
  #pragma unroll
  for (int j = 0; j < 8; j++) {
    uint2 r = *(const uint2*)(mid + t * 36 + j * 4);
    mv[j * 4 + 0] = bf2f((ushort)(r.x & 0xffff));
    mv[j * 4 + 1] = bf2f((ushort)(r.x >> 16));
    mv[j * 4 + 2] = bf2f((ushort)(r.y & 0xffff));
    mv[j * 4 + 3] = bf2f((ushort)(r.y >> 16));
  }
  int oy = by * 16 + (t >> 5), ox = bx * 32 + (t & 31);
  size_t opix = (size_t)oy * WW + ox;
  float* ob = out_base + (size_t)bb * COUT * HWSZ;
  #pragma unroll
  for (int oc = 0; oc < COUT; oc++) {
    float a2 = b2[oc];
    #pragma unroll
    for (int m = 0; m < 32; m++) a2 = fmaf(w2[oc * 32 + m], mv[m], a2);
    if (DO_TANH) a2 = tanhf(a2) * 3.0f;
    ob[(size_t)oc * HWSZ + opix] = a2;
  }
  __syncthreads();
}

// ---------------- heads3: ALL A-operands via rolling global prefetch; ZERO main-loop barriers ----
// Tile k-major: [row 22][g 4][col 38][8e] -> elem = row*1216 + g*304 + col*8   (53,504 B)
// Weights (301 KB total) are L2-resident and read at IDENTICAL addresses by all 8 waves
// -> L1 line reuse x8. Rolling 2-tap-ahead prefetch hides L1/L2 latency (R7's missing piece).
// No wrow, no per-ky staging, no barriers in the ky loop -> waves free-run.
__global__ __launch_bounds__(512, 2) void heads3_kernel(
    const ushort* __restrict__ feats,
    const ushort* __restrict__ wtL, const ushort* __restrict__ wtF,
    const ushort* __restrict__ wtR,
    const float* __restrict__ bbL, const float* __restrict__ bbF,
    const float* __restrict__ bbR,
    const float* __restrict__ w2L, const float* __restrict__ b2L,
    const float* __restrict__ w2F, const float* __restrict__ b2F,
    const float* __restrict__ w2R, const float* __restrict__ b2R,
    float* __restrict__ outL, float* __restrict__ outF, float* __restrict__ outR)
{
  __shared__ __align__(16) char smem[53504];       // tile only; mid reuses it
  ushort* tile = (ushort*)smem;

  int bx = blockIdx.x % 24;                  // 24 tiles of 32 cols
  int by = (blockIdx.x / 24) % 48;           // 48 tiles of 16 rows
  int bb = blockIdx.x / 1152;
  int x0 = bx * 32 - 3, y0 = by * 16 - 3;
  const ushort* fB = feats + (size_t)bb * HWSZ * 32;

  // ---- stage halo tile (22x38), k-major ----
  for (int p = threadIdx.x; p < 22 * 38; p += 512) {
    int r = p / 38, cl = p - r * 38;
    int yy = y0 + r, xx = x0 + cl;
    uint4 q0 = {0,0,0,0}, q1 = {0,0,0,0}, q2 = {0,0,0,0}, q3 = {0,0,0,0};
    if (yy >= 0 && yy < HH && xx >= 0 && xx < WW) {
      const uint4* src = (const uint4*)(fB + ((size_t)yy * WW + xx) * 32);
      q0 = src[0]; q1 = src[1]; q2 = src[2]; q3 = src[3];
    }
    ushort* dst = tile + r * 1216 + cl * 8;
    *(uint4*)(dst +   0) = q0;     // g=0
    *(uint4*)(dst + 304) = q1;     // g=1
    *(uint4*)(dst + 608) = q2;     // g=2
    *(uint4*)(dst + 912) = q3;     // g=3
  }
  __syncthreads();                           // tile ready (only barrier before epilogue)

  int tid = threadIdx.x;
  int l  = tid & 63;
  int wv = tid >> 6;                         // wave 0..7 -> output rows 2wv, 2wv+1
  int q  = l & 31;                           // m row of A / pixel-in-group of B
  int kg = l >> 5;                           // k-octet subgroup
  int qr = q >> 4, qc = q & 15;

  const ushort* pb  = tile + (2 * wv + qr) * 1216 + kg * 304 + qc * 8;
  const ushort* aGL = wtL + q * 32 + kg * 8;
  const ushort* aGF = wtF + q * 32 + kg * 8;
  const ushort* aGR = wtR + q * 32 + kg * 8;

  f32x16 accL[2] = {};
  f32x16 accF[2] = {};
  f32x16 accR[2] = {};

  #pragma unroll 1
  for (int ky = 0; ky < 7; ky++) {
    const ushort* aL = aGL + ky * 7168;
    const ushort* aF = aGF + ky * 7168;
    const ushort* aR = aGR + ky * 7168;
    const ushort* pbrow = pb + ky * 1216;

    // rolling prefetch: taps 0,1 of all three A-streams (static-indexed arrays)
    bhalf8 fL[7][2], fF[7][2], fR[7][2];
    #pragma unroll
    for (int kx = 0; kx < 2; kx++) {
      fL[kx][0] = *(const bhalf8*)(aL + kx * 1024);
      fL[kx][1] = *(const bhalf8*)(aL + kx * 1024 + 16);
      fF[kx][0] = *(const bhalf8*)(aF + kx * 1024);
      fF[kx][1] = *(const bhalf8*)(aF + kx * 1024 + 16);
      fR[kx][0] = *(const bhalf8*)(aR + kx * 1024);
      fR[kx][1] = *(const bhalf8*)(aR + kx * 1024 + 16);
    }

    // preload tap 0 B operands
    bhalf8 cB00 = *(const bhalf8*)(pbrow);
    bhalf8 cB01 = *(const bhalf8*)(pbrow + 608);
    bhalf8 cB10 = *(const bhalf8*)(pbrow + 128);
    bhalf8 cB11 = *(const bhalf8*)(pbrow + 608 + 128);

    #pragma unroll
    for (int kx = 0; kx < 7; kx++) {
      // issue tap kx+2's A-loads (2 taps ahead ~ covers L1/L2 latency)
      if (kx + 2 < 7) {
        const ushort* a2L = aL + (kx + 2) * 1024;
        const ushort* a2F = aF + (kx + 2) * 1024;
        const ushort* a2R = aR + (kx + 2) * 1024;
        fL[kx + 2][0] = *(const bhalf8*)(a2L);
        fL[kx + 2][1] = *(const bhalf8*)(a2L + 16);
        fF[kx + 2][0] = *(const bhalf8*)(a2F);
        fF[kx + 2][1] = *(const bhalf8*)(a2F + 16);
        fR[kx + 2][0] = *(const bhalf8*)(a2R);
        fR[kx + 2][1] = *(const bhalf8*)(a2R + 16);
      }
      // issue tap kx+1's B ds_reads before tap kx's MFMAs
      bhalf8 nB00, nB01, nB10, nB11;
      if (kx < 6) {
        const ushort* p2 = pbrow + (kx + 1) * 8;
        nB00 = *(const bhalf8*)(p2);
        nB01 = *(const bhalf8*)(p2 + 608);
        nB10 = *(const bhalf8*)(p2 + 128);
        nB11 = *(const bhalf8*)(p2 + 608 + 128);
      }

      __builtin_amdgcn_s_setprio(1);
      accL[0] = __builtin_amdgcn_mfma_f32_32x32x16_bf16(fL[kx][0], cB00, accL[0], 0, 0, 0);
      accL[0] = __builtin_amdgcn_mfma_f32_32x32x16_bf16(fL[kx][1], cB01, accL[0], 0, 0, 0);
      accL[1] = __builtin_amdgcn_mfma_f32_32x32x16_bf16(fL[kx][0], cB10, accL[1], 0, 0, 0);
      accL[1] = __builtin_amdgcn_mfma_f32_32x32x16_bf16(fL[kx][1], cB11, accL[1], 0, 0, 0);
      accF[0] = __builtin_amdgcn_mfma_f32_32x32x16_bf16(fF[kx][0], cB00, accF[0], 0, 0, 0);
      accF[0] = __builtin_amdgcn_mfma_f32_32x32x16_bf16(fF[kx][1], cB01, accF[0], 0, 0, 0);
      accF[1] = __builtin_amdgcn_mfma_f32_32x32x16_bf16(fF[kx][0], cB10, accF[1], 0, 0, 0);
      accF[1] = __builtin_amdgcn_mfma_f32_32x32x16_bf16(fF[kx][1], cB11, accF[1], 0, 0, 0);
      accR[0] = __builtin_amdgcn_mfma_f32_32x32x16_bf16(fR[kx][0], cB00, accR[0], 0, 0, 0);
      accR[0] = __builtin_amdgcn_mfma_f32_32x32x16_bf16(fR[kx][1], cB01, accR[0], 0, 0, 0);
      accR[1] = __builtin_amdgcn_mfma_f32_32x32x16_bf16(fR[kx][0], cB10, accR[1], 0, 0, 0);
      accR[1] = __builtin_amdgcn_mfma_f32_32x32x16_bf16(fR[kx][1], cB11, accR[1], 0, 0, 0);
      __builtin_amdgcn_s_setprio(0);

      if (kx < 6) {                          // named-reg swap (rule #20)
        cB00 = nB00; cB01 = nB01; cB10 = nB10; cB11 = nB11;
      }
    }
  }

  __syncthreads();                           // tile no longer needed
  ushort* mid = (ushort*)smem;               // [512][36] bf16 = 36,864 B <= 53,504

  head_epilogue3<2,  false>(accL, bbL, w2L, b2L, outL, mid, wv, qr, qc, kg, by, bx, bb);
  head_epilogue3<20, false>(accF, bbF, w2F, b2F, outF, mid, wv, qr, qc, kg, by, bx, bb);
  head_epilogue3<2,  true >(accR, bbR, w2R, b2R, outR, mid, wv, qr, qc, kg, by, bx, bb);
}

// ---------------- score: single head, 3x3, high occupancy (256 thr) ----------------
template <int COUT, bool DO_TANH>
__device__ inline void head_epilogue_s(
    const f32x16 acc[2], const float* __restrict__ bbh,
    const float* __restrict__ w2, const float* __restrict__ b2,
    float* __restrict__ out_base, float* mid,
    int wv, int qr, int qc, int kg, int by, int bx, int bb)
{
  #pragma unroll
  for (int n = 0; n < 2; n++) {
    int pix = (wv * 4 + 2 * n + qr) * 16 + qc;
    #pragma unroll
    for (int rg = 0; rg < 4; rg++) {
      int m0 = 8 * rg + 4 * kg;
      f32x4 v;
      #pragma unroll
      for (int j = 0; j < 4; j++)
        v[j] = fmaxf(acc[n][rg * 4 + j] + bbh[m0 + j], 0.f);
      *(f32x4*)(mid + pix * 36 + m0) = v;
    }
  }
  __syncthreads();

  int t = threadIdx.x;
  float mv[32];
  #pragma unroll
  for (int j2 = 0; j2 < 8; j2++)
    *(f32x4*)(mv + 4 * j2) = *(const f32x4*)(mid + t * 36 + 4 * j2);

  int oy = by * 16 + (t >> 4), ox = bx * 16 + (t & 15);
  size_t opix = (size_t)oy * WW + ox;
  float* ob = out_base + (size_t)bb * COUT * HWSZ;
  #pragma unroll
  for (int oc = 0; oc < COUT; oc++) {
    float a2 = b2[oc];
    #pragma unroll
    for (int m = 0; m < 32; m++) a2 = fmaf(w2[oc * 32 + m], mv[m], a2);
    if (DO_TANH) a2 = tanhf(a2) * 3.0f;
    ob[(size_t)oc * HWSZ + opix] = a2;
  }
}

__global__ __launch_bounds__(256, 4) void score_kernel(
    const ushort* __restrict__ feats,
    const ushort* __restrict__ wtS, const float* __restrict__ bbS,
    const float* __restrict__ w2S, const float* __restrict__ b2S,
    float* __restrict__ outS)
{
  constexpr int TW = 18, CPAD = 40;
  constexpr int SMEM_BYTES = 256 * 36 * 4;
  __shared__ __align__(16) char smem[SMEM_BYTES];
  ushort* tile = (ushort*)smem;

  int bx = blockIdx.x % 48;
  int by = (blockIdx.x / 48) % 48;
  int bb = blockIdx.x / 2304;
  int x0 = bx * 16 - 1, y0 = by * 16 - 1;
  const ushort* fB = feats + (size_t)bb * HWSZ * 32;

  for (int p = threadIdx.x; p < TW * TW; p += 256) {
    int py = p / TW, pxx = p % TW;
    int yy = y0 + py, xx = x0 + pxx;
    uint4 q0 = {0,0,0,0}, q1 = {0,0,0,0}, q2 = {0,0,0,0}, q3 = {0,0,0,0};
    if (yy >= 0 && yy < HH && xx >= 0 && xx < WW) {
      const uint4* src = (const uint4*)(fB + ((size_t)yy * WW + xx) * 32);
      q0 = src[0]; q1 = src[1]; q2 = src[2]; q3 = src[3];
    }
    uint4* dst = (uint4*)(tile + (size_t)p * CPAD);
    dst[0] = q0; dst[1] = q1; dst[2] = q2; dst[3] = q3;
  }
  __syncthreads();

  int l  = threadIdx.x & 63;
  int wv = threadIdx.x >> 6;
  int q  = l & 31;
  int kg = l >> 5;
  int qr = q >> 4, qc = q & 15;

  const ushort* pb = tile + ((wv * 4 + qr) * TW + qc) * CPAD + kg * 8;
  const int aoff = q * 32 + kg * 8;

  f32x16 acc[2] = {};

  #pragma unroll
  for (int ky = 0; ky < 3; ky++) {
    #pragma unroll
    for (int kx = 0; kx < 3; kx++) {
      const int tap = ky * 3 + kx;
      bhalf8 a0[2];
      #pragma unroll
      for (int kh = 0; kh < 2; kh++)
        a0[kh] = *(const bhalf8*)(wtS + tap * 1024 + aoff + kh * 16);
      #pragma unroll
      for (int n = 0; n < 2; n++) {
        #pragma unroll
        for (int kh = 0; kh < 2; kh++) {
          bhalf8 bf = *(const bhalf8*)(pb + (ky * TW + kx) * CPAD
                                          + n * 2 * TW * CPAD + kh * 16);
          acc[n] = __builtin_amdgcn_mfma_f32_32x32x16_bf16(a0[kh], bf, acc[n], 0, 0, 0);
        }
      }
    }
  }

  __syncthreads();
  float* mid = (float*)smem;
  head_epilogue_s<2, false>(acc, bbS, w2S, b2S, outS, mid, wv, qr, qc, kg, by, bx, bb);
}

extern "C" void kernel_launch(void* const* d_in, const int* in_sizes, int n_in,
                              void* d_out, int out_size, void* d_ws, size_t ws_size,
                              hipStream_t stream) {
  const float* input = (const float*)d_in[0];
  const float* bb_w  = (const float*)d_in[1];
  const float* bb_b  = (const float*)d_in[2];

  ushort* feats = (ushort*)d_ws;                             // 2*HW*32 bf16 = 75.5 MB
  char* base = (char*)d_ws;
  const size_t FEATS_BYTES = (size_t)2 * HWSZ * 32 * 2;
  const size_t WT_STRIDE_E = 49 * 1024;                      // elements per head slot
  ushort* wT0 = (ushort*)(base + FEATS_BYTES);
  float*  bb0 = (float*)(base + FEATS_BYTES + 4 * WT_STRIDE_E * 2);
  (void)out_size; (void)ws_size; (void)n_in; (void)in_sizes;

  float* out = (float*)d_out;
  // output chunks (elements): scores @0, loc @4HW, ref @8HW, four @12HW
  float* outS = out;
  float* outL = out + (size_t)4  * HWSZ;
  float* outR = out + (size_t)8  * HWSZ;
  float* outF = out + (size_t)12 * HWSZ;

  // merged weight transform (grid.y = head: 0 score, 1 loc, 2 four, 3 ref)
  dim3 wxgrid(196, 4);
  wxform_all_kernel<<<wxgrid, 256, 0, stream>>>(
      (const float*)d_in[3],  (const float*)d_in[4],  (const float*)d_in[5],  (const float*)d_in[6],
      (const float*)d_in[9],  (const float*)d_in[10], (const float*)d_in[11], (const float*)d_in[12],
      (const float*)d_in[15], (const float*)d_in[16], (const float*)d_in[17], (const float*)d_in[18],
      (const float*)d_in[21], (const float*)d_in[22], (const float*)d_in[23], (const float*)d_in[24],
      wT0, bb0, WT_STRIDE_E);

  backbone_kernel<<<4608, 256, 0, stream>>>(input, bb_w, bb_b, feats);

  const ushort* wtS = wT0 + 0 * WT_STRIDE_E;
  const ushort* wtL = wT0 + 1 * WT_STRIDE_E;
  const ushort* wtF = wT0 + 2 * WT_STRIDE_E;
  const ushort* wtR = wT0 + 3 * WT_STRIDE_E;

  heads3_kernel<<<2 * 48 * 24, 512, 0, stream>>>(
      feats, wtL, wtF, wtR,
      bb0 + 32, bb0 + 64, bb0 + 96,
      (const float*)d_in[13], (const float*)d_in[14],
      (const float*)d_in[19], (const float*)d_in[20],
      (const float*)d_in[25], (const float*)d_in[26],
      outL, outF, outR);

  score_kernel<<<2 * 48 * 48, 256, 0, stream>>>(
      feats, wtS, bb0 + 0,
      (const float*)d_in[7], (const float*)d_in[8], outS);
}

// Round 16
// 409.865 us; speedup vs baseline: 1.1747x; 1.1747x over previous
//
#include <hip/hip_runtime.h>
#include <hip/hip_bf16.h>
#include <cmath>

#define HH 768
#define WW 768
#define HWSZ (768*768)

typedef __attribute__((ext_vector_type(8))) short bhalf8;   // 8 bf16 in 4 VGPRs
typedef __attribute__((ext_vector_type(4))) float f32x4;
typedef __attribute__((ext_vector_type(16))) float f32x16;

__device__ inline ushort f2bf(float f) {
  __hip_bfloat16 h = __float2bfloat16(f);
  return *reinterpret_cast<ushort*>(&h);
}
__device__ inline float bf2f(ushort u) {
  union { unsigned int i; float f; } v; v.i = ((unsigned int)u) << 16; return v.f;
}

// ---------------- merged weight transform for all 4 heads ----------------
__global__ __launch_bounds__(256) void wxform_all_kernel(
    const float* __restrict__ w1S, const float* __restrict__ b1S,
    const float* __restrict__ sS,  const float* __restrict__ tS,
    const float* __restrict__ w1L, const float* __restrict__ b1L,
    const float* __restrict__ sL,  const float* __restrict__ tL,
    const float* __restrict__ w1F, const float* __restrict__ b1F,
    const float* __restrict__ sF,  const float* __restrict__ tF,
    const float* __restrict__ w1R, const float* __restrict__ b1R,
    const float* __restrict__ sR,  const float* __restrict__ tR,
    ushort* __restrict__ wT0, float* __restrict__ bb0, size_t wt_stride_elems)
{
  int h = blockIdx.y;
  const float *w1, *b1, *s, *t;
  int npos;
  if (h == 0)      { w1 = w1S; b1 = b1S; s = sS; t = tS; npos = 9;  }
  else if (h == 1) { w1 = w1L; b1 = b1L; s = sL; t = tL; npos = 49; }
  else if (h == 2) { w1 = w1F; b1 = b1F; s = sF; t = tF; npos = 49; }
  else             { w1 = w1R; b1 = b1R; s = sR; t = tR; npos = 49; }

  ushort* wT = wT0 + (size_t)h * wt_stride_elems;
  float*  bb = bb0 + h * 32;

  int i = blockIdx.x * 256 + threadIdx.x;
  if (i < npos * 1024) {
    int pos = i >> 10, mc = i & 1023, m = mc >> 5, c = mc & 31;
    wT[i] = f2bf(w1[(m * 32 + c) * npos + pos] * s[m]);
  }
  if (blockIdx.x == 0 && i < 32) bb[i] = b1[i] * s[i] + t[i];
}

// ---------------- backbone: conv3x3 (3->32) + bias + relu, feats[b][y][x][c] bf16 ----------------
__global__ __launch_bounds__(256) void backbone_kernel(
    const float* __restrict__ x, const float* __restrict__ w,
    const float* __restrict__ bias, ushort* __restrict__ feats)
{
  int p = blockIdx.x * 256 + threadIdx.x;          // 0 .. 2*HW-1
  int bb  = p / HWSZ;
  int rem = p - bb * HWSZ;
  int y   = rem / WW;
  int xx  = rem - y * WW;
  const float* xb = x + (size_t)bb * 3 * HWSZ;

  float v[3][3][3];
  #pragma unroll
  for (int c = 0; c < 3; c++)
    #pragma unroll
    for (int dy = 0; dy < 3; dy++)
      #pragma unroll
      for (int dx = 0; dx < 3; dx++) {
        int yy = y + dy - 1, xq = xx + dx - 1;
        v[c][dy][dx] = (yy >= 0 && yy < HH && xq >= 0 && xq < WW)
                         ? xb[(size_t)c * HWSZ + yy * WW + xq] : 0.f;
      }

  union { ushort u[32]; uint4 q[4]; } pk;
  #pragma unroll
  for (int o = 0; o < 32; o++) {
    float acc = bias[o];
    #pragma unroll
    for (int c = 0; c < 3; c++)
      #pragma unroll
      for (int dy = 0; dy < 3; dy++)
        #pragma unroll
        for (int dx = 0; dx < 3; dx++)
          acc = fmaf(w[((o * 3 + c) * 3 + dy) * 3 + dx], v[c][dy][dx], acc);
    pk.u[o] = f2bf(fmaxf(acc, 0.f));
  }
  uint4* dst = (uint4*)(feats + ((size_t)bb * HWSZ + rem) * 32);
  #pragma unroll
  for (int i = 0; i < 4; i++) dst[i] = pk.q[i];
}

// ---------------- heads3 epilogue: BN+relu -> bf16 mids in LDS -> 1x1 conv -> store ----
template <int COUT, bool DO_TANH>
__device__ inline void head_epilogue3(
    const f32x16 acc[2], const float* __restrict__ bbh,
    const float* __restrict__ w2, const float* __restrict__ b2,
    float* __restrict__ out_base, ushort* mid,
    int wv, int qr, int qc, int kg, int by, int bx, int bb)
{
  #pragma unroll
  for (int n = 0; n < 2; n++) {
    int px = (2 * wv + qr) * 32 + n * 16 + qc;
    #pragma unroll
    for (int rg = 0; rg < 4; rg++) {
      int m0 = 8 * rg + 4 * kg;
      ushort u[4];
      #pragma unroll
      for (int j = 0; j < 4; j++)
        u[j] = f2bf(fmaxf(acc[n][rg * 4 + j] + bbh[m0 + j], 0.f));
      uint2 pkv;
      pkv.x = (unsigned int)u[0] | ((unsigned int)u[1] << 16);
      pkv.y = (unsigned int)u[2] | ((unsigned int)u[3] << 16);
      *(uint2*)(mid + px * 36 + m0) = pkv;
    }
  }
  __syncthreads();

  int t = threadIdx.x;                       // one pixel per thread (512 px)
  float mv[32];
  #pragma unroll
  for (int j = 0; j < 8; j++) {
    uint2 r = *(const uint2*)(mid + t * 36 + j * 4);
    mv[j * 4 + 0] = bf2f((ushort)(r.x & 0xffff));
    mv[j * 4 + 1] = bf2f((ushort)(r.x >> 16));
    mv[j * 4 + 2] = bf2f((ushort)(r.y & 0xffff));
    mv[j * 4 + 3] = bf2f((ushort)(r.y >> 16));
  }
  int oy = by * 16 + (t >> 5), ox = bx * 32 + (t & 31);
  size_t opix = (size_t)oy * WW + ox;
  float* ob = out_base + (size_t)bb * COUT * HWSZ;
  #pragma unroll
  for (int oc = 0; oc < COUT; oc++) {
    float a2 = b2[oc];
    #pragma unroll
    for (int m = 0; m < 32; m++) a2 = fmaf(w2[oc * 32 + m], mv[m], a2);
    if (DO_TANH) a2 = tanhf(a2) * 3.0f;
    ob[(size_t)oc * HWSZ + opix] = a2;
  }
  __syncthreads();
}

// ---------------- heads3: R13 structure + kh-outer MFMA interleave (dep-distance 6) ----------------
// Tile k-major: [row 22][g 4][col 38][8e] -> elem = row*1216 + g*304 + col*8   (53,504 B)
// wrow[2] bufs: [kx 7][h 2][g 4][m 32][8e] -> elem = kx*2048 + h*1024 + g*256 + m*8 (28,672 B each)
__global__ __launch_bounds__(512, 2) void heads3_kernel(
    const ushort* __restrict__ feats,
    const ushort* __restrict__ wtL, const ushort* __restrict__ wtF,
    const ushort* __restrict__ wtR,
    const float* __restrict__ bbL, const float* __restrict__ bbF,
    const float* __restrict__ bbR,
    const float* __restrict__ w2L, const float* __restrict__ b2L,
    const float* __restrict__ w2F, const float* __restrict__ b2F,
    const float* __restrict__ w2R, const float* __restrict__ b2R,
    float* __restrict__ outL, float* __restrict__ outF, float* __restrict__ outR)
{
  __shared__ __align__(16) char smem[53504 + 2 * 28672];   // 110,848 B
  ushort* tile  = (ushort*)smem;
  ushort* wrow0 = (ushort*)(smem + 53504);
  ushort* wrow1 = (ushort*)(smem + 53504 + 28672);

  int bx = blockIdx.x % 24;                  // 24 tiles of 32 cols
  int by = (blockIdx.x / 24) % 48;           // 48 tiles of 16 rows
  int bb = blockIdx.x / 1152;
  int x0 = bx * 32 - 3, y0 = by * 16 - 3;
  const ushort* fB = feats + (size_t)bb * HWSZ * 32;

  // ---- stage halo tile (22x38), k-major ----
  for (int p = threadIdx.x; p < 22 * 38; p += 512) {
    int r = p / 38, cl = p - r * 38;
    int yy = y0 + r, xx = x0 + cl;
    uint4 q0 = {0,0,0,0}, q1 = {0,0,0,0}, q2 = {0,0,0,0}, q3 = {0,0,0,0};
    if (yy >= 0 && yy < HH && xx >= 0 && xx < WW) {
      const uint4* src = (const uint4*)(fB + ((size_t)yy * WW + xx) * 32);
      q0 = src[0]; q1 = src[1]; q2 = src[2]; q3 = src[3];
    }
    ushort* dst = tile + r * 1216 + cl * 8;
    *(uint4*)(dst +   0) = q0;     // g=0
    *(uint4*)(dst + 304) = q1;     // g=1
    *(uint4*)(dst + 608) = q2;     // g=2
    *(uint4*)(dst + 912) = q3;     // g=3
  }

  int tid = threadIdx.x;
  int l  = tid & 63;
  int wv = tid >> 6;                         // wave 0..7 -> output rows 2wv, 2wv+1
  int q  = l & 31;                           // m row of A / pixel-in-group of B
  int kg = l >> 5;                           // k-octet subgroup
  int qr = q >> 4, qc = q & 15;

  const ushort* pb  = tile + (2 * wv + qr) * 1216 + kg * 304 + qc * 8;
  const int aOff = kg * 256 + q * 8;         // per-lane A offset within wrow buf
  const ushort* aGR = wtR + q * 32 + kg * 8;

  // ---- staging decode: 1792 16B-chunks/ky; chunk c -> dst elem c*8 ----
  const ushort *stp0, *stp1, *stp2, *stp3;
  {
    int c, kx, h, g, m;
    c = tid;         kx = c >> 8; h = (c >> 7) & 1; g = (c >> 5) & 3; m = c & 31;
    stp0 = (h ? wtF : wtL) + kx * 1024 + m * 32 + g * 8;
    c = 512 + tid;   kx = c >> 8; h = (c >> 7) & 1; g = (c >> 5) & 3; m = c & 31;
    stp1 = (h ? wtF : wtL) + kx * 1024 + m * 32 + g * 8;
    c = 1024 + tid;  kx = c >> 8; h = (c >> 7) & 1; g = (c >> 5) & 3; m = c & 31;
    stp2 = (h ? wtF : wtL) + kx * 1024 + m * 32 + g * 8;
    c = 1536 + tid;  kx = c >> 8; h = (c >> 7) & 1; g = (c >> 5) & 3; m = c & 31;
    stp3 = (h ? wtF : wtL) + kx * 1024 + m * 32 + g * 8;   // valid only if tid < 256
  }
  const bool st3 = (tid < 256);

  // prologue: load+write ky=0 into wrow0
  {
    bhalf8 v0 = *(const bhalf8*)(stp0);
    bhalf8 v1 = *(const bhalf8*)(stp1);
    bhalf8 v2 = *(const bhalf8*)(stp2);
    *(bhalf8*)(wrow0 + (size_t)tid * 8) = v0;
    *(bhalf8*)(wrow0 + (size_t)(512 + tid) * 8) = v1;
    *(bhalf8*)(wrow0 + (size_t)(1024 + tid) * 8) = v2;
    if (st3) {
      bhalf8 v3 = *(const bhalf8*)(stp3);
      *(bhalf8*)(wrow0 + (size_t)(1536 + tid) * 8) = v3;
    }
  }
  __syncthreads();                           // tile + wrow0 ready

  f32x16 accL[2] = {};
  f32x16 accF[2] = {};
  f32x16 accR[2] = {};

  #pragma unroll 1
  for (int ky = 0; ky < 7; ky++) {
    ushort* bufR = (ky & 1) ? wrow1 : wrow0;   // read buffer (this ky)
    ushort* bufW = (ky & 1) ? wrow0 : wrow1;   // write buffer (ky+1)
    const ushort* aB = bufR + aOff;
    const ushort* aR = aGR + ky * 7168;
    const ushort* pbrow = pb + ky * 1216;

    // issue ky+1 weight loads (fly under this ky's compute)
    bhalf8 pB0, pB1, pB2, pB3;
    if (ky < 6) {
      pB0 = *(const bhalf8*)(stp0 + (ky + 1) * 7168);
      pB1 = *(const bhalf8*)(stp1 + (ky + 1) * 7168);
      pB2 = *(const bhalf8*)(stp2 + (ky + 1) * 7168);
      if (st3) pB3 = *(const bhalf8*)(stp3 + (ky + 1) * 7168);
    }

    // rolling prefetch for ref's global A-stream
    bhalf8 fR[7][2];
    #pragma unroll
    for (int kx = 0; kx < 2; kx++) {
      fR[kx][0] = *(const bhalf8*)(aR + kx * 1024);
      fR[kx][1] = *(const bhalf8*)(aR + kx * 1024 + 16);
    }

    // preload tap 0 LDS operands (cur regs)
    bhalf8 cL0 = *(const bhalf8*)(aB);
    bhalf8 cL1 = *(const bhalf8*)(aB + 512);
    bhalf8 cF0 = *(const bhalf8*)(aB + 1024);
    bhalf8 cF1 = *(const bhalf8*)(aB + 1536);
    bhalf8 cB00 = *(const bhalf8*)(pbrow);
    bhalf8 cB01 = *(const bhalf8*)(pbrow + 608);
    bhalf8 cB10 = *(const bhalf8*)(pbrow + 128);
    bhalf8 cB11 = *(const bhalf8*)(pbrow + 608 + 128);

    #pragma unroll
    for (int kx = 0; kx < 7; kx++) {
      // issue tap kx+1's 8 ds_reads BEFORE tap kx's MFMAs (SW pipeline)
      bhalf8 nL0, nL1, nF0, nF1, nB00, nB01, nB10, nB11;
      if (kx < 6) {
        const ushort* a2 = aB + (kx + 1) * 2048;
        nL0 = *(const bhalf8*)(a2);
        nL1 = *(const bhalf8*)(a2 + 512);
        nF0 = *(const bhalf8*)(a2 + 1024);
        nF1 = *(const bhalf8*)(a2 + 1536);
        const ushort* p2 = pbrow + (kx + 1) * 8;
        nB00 = *(const bhalf8*)(p2);
        nB01 = *(const bhalf8*)(p2 + 608);
        nB10 = *(const bhalf8*)(p2 + 128);
        nB11 = *(const bhalf8*)(p2 + 608 + 128);
      }
      if (kx + 2 < 7) {
        fR[kx + 2][0] = *(const bhalf8*)(aR + (kx + 2) * 1024);
        fR[kx + 2][1] = *(const bhalf8*)(aR + (kx + 2) * 1024 + 16);
      }

      // kh-OUTER interleave: same-acc MFMAs are 6 apart (dep distance ~50 cyc > latency)
      __builtin_amdgcn_s_setprio(1);
      accL[0] = __builtin_amdgcn_mfma_f32_32x32x16_bf16(cL0, cB00, accL[0], 0, 0, 0);
      accL[1] = __builtin_amdgcn_mfma_f32_32x32x16_bf16(cL0, cB10, accL[1], 0, 0, 0);
      accF[0] = __builtin_amdgcn_mfma_f32_32x32x16_bf16(cF0, cB00, accF[0], 0, 0, 0);
      accF[1] = __builtin_amdgcn_mfma_f32_32x32x16_bf16(cF0, cB10, accF[1], 0, 0, 0);
      accR[0] = __builtin_amdgcn_mfma_f32_32x32x16_bf16(fR[kx][0], cB00, accR[0], 0, 0, 0);
      accR[1] = __builtin_amdgcn_mfma_f32_32x32x16_bf16(fR[kx][0], cB10, accR[1], 0, 0, 0);
      accL[0] = __builtin_amdgcn_mfma_f32_32x32x16_bf16(cL1, cB01, accL[0], 0, 0, 0);
      accL[1] = __builtin_amdgcn_mfma_f32_32x32x16_bf16(cL1, cB11, accL[1], 0, 0, 0);
      accF[0] = __builtin_amdgcn_mfma_f32_32x32x16_bf16(cF1, cB01, accF[0], 0, 0, 0);
      accF[1] = __builtin_amdgcn_mfma_f32_32x32x16_bf16(cF1, cB11, accF[1], 0, 0, 0);
      accR[0] = __builtin_amdgcn_mfma_f32_32x32x16_bf16(fR[kx][1], cB01, accR[0], 0, 0, 0);
      accR[1] = __builtin_amdgcn_mfma_f32_32x32x16_bf16(fR[kx][1], cB11, accR[1], 0, 0, 0);
      __builtin_amdgcn_s_setprio(0);

      if (kx < 6) {                          // named-reg swap (rule #20)
        cL0 = nL0; cL1 = nL1; cF0 = nF0; cF1 = nF1;
        cB00 = nB00; cB01 = nB01; cB10 = nB10; cB11 = nB11;
      }
    }

    // write ky+1 weights into the idle buffer (no race: readers use bufR)
    if (ky < 6) {
      *(bhalf8*)(bufW + (size_t)tid * 8) = pB0;
      *(bhalf8*)(bufW + (size_t)(512 + tid) * 8) = pB1;
      *(bhalf8*)(bufW + (size_t)(1024 + tid) * 8) = pB2;
      if (st3) *(bhalf8*)(bufW + (size_t)(1536 + tid) * 8) = pB3;
    }
    __syncthreads();                         // single barrier per ky
  }

  ushort* mid = (ushort*)smem;               // [512][36] bf16 = 36,864 B

  head_epilogue3<2,  false>(accL, bbL, w2L, b2L, outL, mid, wv, qr, qc, kg, by, bx, bb);
  head_epilogue3<20, false>(accF, bbF, w2F, b2F, outF, mid, wv, qr, qc, kg, by, bx, bb);
  head_epilogue3<2,  true >(accR, bbR, w2R, b2R, outR, mid, wv, qr, qc, kg, by, bx, bb);
}

// ---------------- score: single head, 3x3, high occupancy (256 thr) ----------------
template <int COUT, bool DO_TANH>
__device__ inline void head_epilogue_s(
    const f32x16 acc[2], const float* __restrict__ bbh,
    const float* __restrict__ w2, const float* __restrict__ b2,
    float* __restrict__ out_base, float* mid,
    int wv, int qr, int qc, int kg, int by, int bx, int bb)
{
  #pragma unroll
  for (int n = 0; n < 2; n++) {
    int pix = (wv * 4 + 2 * n + qr) * 16 + qc;
    #pragma unroll
    for (int rg = 0; rg < 4; rg++) {
      int m0 = 8 * rg + 4 * kg;
      f32x4 v;
      #pragma unroll
      for (int j = 0; j < 4; j++)
        v[j] = fmaxf(acc[n][rg * 4 + j] + bbh[m0 + j], 0.f);
      *(f32x4*)(mid + pix * 36 + m0) = v;
    }
  }
  __syncthreads();

  int t = threadIdx.x;
  float mv[32];
  #pragma unroll
  for (int j2 = 0; j2 < 8; j2++)
    *(f32x4*)(mv + 4 * j2) = *(const f32x4*)(mid + t * 36 + 4 * j2);

  int oy = by * 16 + (t >> 4), ox = bx * 16 + (t & 15);
  size_t opix = (size_t)oy * WW + ox;
  float* ob = out_base + (size_t)bb * COUT * HWSZ;
  #pragma unroll
  for (int oc = 0; oc < COUT; oc++) {
    float a2 = b2[oc];
    #pragma unroll
    for (int m = 0; m < 32; m++) a2 = fmaf(w2[oc * 32 + m], mv[m], a2);
    if (DO_TANH) a2 = tanhf(a2) * 3.0f;
    ob[(size_t)oc * HWSZ + opix] = a2;
  }
}

__global__ __launch_bounds__(256, 4) void score_kernel(
    const ushort* __restrict__ feats,
    const ushort* __restrict__ wtS, const float* __restrict__ bbS,
    const float* __restrict__ w2S, const float* __restrict__ b2S,
    float* __restrict__ outS)
{
  constexpr int TW = 18, CPAD = 40;
  constexpr int SMEM_BYTES = 256 * 36 * 4;
  __shared__ __align__(16) char smem[SMEM_BYTES];
  ushort* tile = (ushort*)smem;

  int bx = blockIdx.x % 48;
  int by = (blockIdx.x / 48) % 48;
  int bb = blockIdx.x / 2304;
  int x0 = bx * 16 - 1, y0 = by * 16 - 1;
  const ushort* fB = feats + (size_t)bb * HWSZ * 32;

  for (int p = threadIdx.x; p < TW * TW; p += 256) {
    int py = p / TW, pxx = p % TW;
    int yy = y0 + py, xx = x0 + pxx;
    uint4 q0 = {0,0,0,0}, q1 = {0,0,0,0}, q2 = {0,0,0,0}, q3 = {0,0,0,0};
    if (yy >= 0 && yy < HH && xx >= 0 && xx < WW) {
      const uint4* src = (const uint4*)(fB + ((size_t)yy * WW + xx) * 32);
      q0 = src[0]; q1 = src[1]; q2 = src[2]; q3 = src[3];
    }
    uint4* dst = (uint4*)(tile + (size_t)p * CPAD);
    dst[0] = q0; dst[1] = q1; dst[2] = q2; dst[3] = q3;
  }
  __syncthreads();

  int l  = threadIdx.x & 63;
  int wv = threadIdx.x >> 6;
  int q  = l & 31;
  int kg = l >> 5;
  int qr = q >> 4, qc = q & 15;

  const ushort* pb = tile + ((wv * 4 + qr) * TW + qc) * CPAD + kg * 8;
  const int aoff = q * 32 + kg * 8;

  f32x16 acc[2] = {};

  #pragma unroll
  for (int ky = 0; ky < 3; ky++) {
    #pragma unroll
    for (int kx = 0; kx < 3; kx++) {
      const int tap = ky * 3 + kx;
      bhalf8 a0[2];
      #pragma unroll
      for (int kh = 0; kh < 2; kh++)
        a0[kh] = *(const bhalf8*)(wtS + tap * 1024 + aoff + kh * 16);
      #pragma unroll
      for (int n = 0; n < 2; n++) {
        #pragma unroll
        for (int kh = 0; kh < 2; kh++) {
          bhalf8 bf = *(const bhalf8*)(pb + (ky * TW + kx) * CPAD
                                          + n * 2 * TW * CPAD + kh * 16);
          acc[n] = __builtin_amdgcn_mfma_f32_32x32x16_bf16(a0[kh], bf, acc[n], 0, 0, 0);
        }
      }
    }
  }

  __syncthreads();
  float* mid = (float*)smem;
  head_epilogue_s<2, false>(acc, bbS, w2S, b2S, outS, mid, wv, qr, qc, kg, by, bx, bb);
}

extern "C" void kernel_launch(void* const* d_in, const int* in_sizes, int n_in,
                              void* d_out, int out_size, void* d_ws, size_t ws_size,
                              hipStream_t stream) {
  const float* input = (const float*)d_in[0];
  const float* bb_w  = (const float*)d_in[1];
  const float* bb_b  = (const float*)d_in[2];

  ushort* feats = (ushort*)d_ws;                             // 2*HW*32 bf16 = 75.5 MB
  char* base = (char*)d_ws;
  const size_t FEATS_BYTES = (size_t)2 * HWSZ * 32 * 2;
  const size_t WT_STRIDE_E = 49 * 1024;                      // elements per head slot
  ushort* wT0 = (ushort*)(base + FEATS_BYTES);
  float*  bb0 = (float*)(base + FEATS_BYTES + 4 * WT_STRIDE_E * 2);
  (void)out_size; (void)ws_size; (void)n_in; (void)in_sizes;

  float* out = (float*)d_out;
  // output chunks (elements): scores @0, loc @4HW, ref @8HW, four @12HW
  float* outS = out;
  float* outL = out + (size_t)4  * HWSZ;
  float* outR = out + (size_t)8  * HWSZ;
  float* outF = out + (size_t)12 * HWSZ;

  // merged weight transform (grid.y = head: 0 score, 1 loc, 2 four, 3 ref)
  dim3 wxgrid(196, 4);
  wxform_all_kernel<<<wxgrid, 256, 0, stream>>>(
      (const float*)d_in[3],  (const float*)d_in[4],  (const float*)d_in[5],  (const float*)d_in[6],
      (const float*)d_in[9],  (const float*)d_in[10], (const float*)d_in[11], (const float*)d_in[12],
      (const float*)d_in[15], (const float*)d_in[16], (const float*)d_in[17], (const float*)d_in[18],
      (const float*)d_in[21], (const float*)d_in[22], (const float*)d_in[23], (const float*)d_in[24],
      wT0, bb0, WT_STRIDE_E);

  backbone_kernel<<<4608, 256, 0, stream>>>(input, bb_w, bb_b, feats);

  const ushort* wtS = wT0 + 0 * WT_STRIDE_E;
  const ushort* wtL = wT0 + 1 * WT_STRIDE_E;
  const ushort* wtF = wT0 + 2 * WT_STRIDE_E;
  const ushort* wtR = wT0 + 3 * WT_STRIDE_E;

  heads3_kernel<<<2 * 48 * 24, 512, 0, stream>>>(
      feats, wtL, wtF, wtR,
      bb0 + 32, bb0 + 64, bb0 + 96,
      (const float*)d_in[13], (const float*)d_in[14],
      (const float*)d_in[19], (const float*)d_in[20],
      (const float*)d_in[25], (const float*)d_in[26],
      outL, outF, outR);

  score_kernel<<<2 * 48 * 48, 256, 0, stream>>>(
      feats, wtS, bb0 + 0,
      (const float*)d_in[7], (const float*)d_in[8], outS);
}